// Round 4
// baseline (64.290 us; speedup 1.0000x reference)
//
#include <hip/hip_runtime.h>
#include <math.h>
#include <stdint.h>

#define THRES 0.12f
#define MAXDETS 3
#define RES 7
#define NCELL (RES * RES)
#define NSLOT (NCELL * MAXDETS)

// key = (score_bits << 32) | (0xFFFFFFFF - idx), sentinel = 0 (empty).
// All kept scores are > 0.12 > 0 -> positive fp32 bit patterns are
// order-preserving as unsigned ints; smaller idx -> larger low word,
// matching top_k's index-ascending tie-break.
//
// Filter correctness: slots only increase under atomicMax (monotone), and any
// value in slot[2] was displaced twice, i.e. has >=2 strictly larger keys ->
// slot[2] snapshot <= final 3rd max at all times. Keys are unique, so
// cur <= snapshot implies cur is strictly below the final top-3: safe to skip.
__global__ __launch_bounds__(1024)
void frcnn_post(const float* __restrict__ boxes,   // [B,N,4]
                const int* __restrict__ labels,    // [B,N]
                const float* __restrict__ scores,  // [B,N]
                const int* __restrict__ Hp,
                const int* __restrict__ Wp,
                float* __restrict__ out,           // classes [B*3*49] ++ boxes [B*15*49]
                int B, int N)
{
    __shared__ unsigned long long slots[NSLOT];  // [cell][k], sorted desc by cascade
    extern __shared__ char smem[];
    float4* snb = (float4*)smem;                 // normalized boxes [N]
    int* slab = (int*)(smem + (size_t)N * sizeof(float4));  // labels [N]

    const int b = blockIdx.x;
    const int tid = threadIdx.x;

    const float Hf = (float)Hp[0];
    const float ar = (float)((double)Wp[0] / (double)Hp[0]);

    const float* bb = boxes + (size_t)b * N * 4;
    const float* ss = scores + (size_t)b * N;
    const int*   ll = labels + (size_t)b * N;

    // init slots to sentinel
    if (tid < NSLOT) slots[tid] = 0ULL;
    __syncthreads();

    // ---- Phase 1: one pass; all three loads independent (parallel issue) ----
    for (int n = tid; n < N; n += blockDim.x) {
        float s = ss[n];                       // independent load 1
        float4 v = ((const float4*)bb)[n];     // independent load 2 (unconditional)
        int lab = ll[n];                       // independent load 3
        float nb0 = v.x / Hf, nb1 = v.y / Hf, nb2 = v.z / Hf, nb3 = v.w / Hf;
        snb[n] = make_float4(nb0, nb1, nb2, nb3);
        slab[n] = lab;
        if (s > THRES) {
            float cx = (nb0 + nb2) * 0.5f;
            float cy = (nb1 + nb3) * 0.5f;
            int px = 0, py = 0;
#pragma unroll
            for (int j = 1; j < RES; ++j) {
                float bj = (float)j / (float)RES;   // bins = arange(1,7)/7 in fp32
                px += (cx >= ar * bj) ? 1 : 0;      // digitize, right=False
                py += (cy >= bj) ? 1 : 0;
            }
            int bin = py * RES + px;
            unsigned long long cur =
                ((unsigned long long)(unsigned int)__float_as_int(s) << 32)
                | (unsigned long long)(0xFFFFFFFFu - (unsigned int)n);
            unsigned long long* sl = &slots[bin * MAXDETS];
            // monotone-safe pre-filter: skip atomics if provably below top-3
            if (cur > sl[MAXDETS - 1]) {
#pragma unroll
                for (int k = 0; k < MAXDETS; ++k) {
                    // cheap snapshot test per level (monotone-safe, same proof)
                    if (k > 0 && cur <= sl[MAXDETS - 1]) break;
                    unsigned long long old = atomicMax(&sl[k], cur);
                    cur = (old < cur) ? old : cur;  // loser cascades to next slot
                    if (cur == 0ULL) break;
                }
            }
        }
    }
    __syncthreads();

    // ---- Phase 2: 147 threads emit (cell, k); LDS-only reads ----
    if (tid < NSLOT) {
        const int k = tid / NCELL;      // det slot 0..2
        const int cell = tid % NCELL;   // 0..48
        unsigned long long key = slots[cell * MAXDETS + k];
        float f0 = -1.0f, f1 = -1.0f, f2 = -1.0f, f3 = -1.0f, f4 = -1.0f;
        int cls = 0;
        if (key != 0ULL) {
            float s = __int_as_float((int)(key >> 32));
            int idx = (int)(0xFFFFFFFFu - (unsigned int)(key & 0xFFFFFFFFULL));
            float4 v = snb[idx];
            f0 = s;
            f1 = (v.z - v.x) / ar;
            f2 = v.w - v.y;
            f3 = v.x / ar;
            f4 = v.y;
            cls = slab[idx];
        }
        // classes_out[b, k, cell] — threads 0..146 write contiguously
        out[(size_t)b * NSLOT + k * NCELL + cell] = (float)cls;
        // boxes_out[b, k*5 + f, cell]
        float* ob = out + (size_t)B * NSLOT
                        + (size_t)b * (MAXDETS * 5 * NCELL)
                        + (k * 5) * NCELL + cell;
        ob[0 * NCELL] = f0;
        ob[1 * NCELL] = f1;
        ob[2 * NCELL] = f2;
        ob[3 * NCELL] = f3;
        ob[4 * NCELL] = f4;
    }
}

extern "C" void kernel_launch(void* const* d_in, const int* in_sizes, int n_in,
                              void* d_out, int out_size, void* d_ws, size_t ws_size,
                              hipStream_t stream) {
    const float* boxes  = (const float*)d_in[0];
    const int*   labels = (const int*)d_in[1];
    const float* scores = (const float*)d_in[2];
    const int*   Hp     = (const int*)d_in[3];
    const int*   Wp     = (const int*)d_in[4];
    float* out = (float*)d_out;

    int B = out_size / (NCELL * (MAXDETS + MAXDETS * 5));  // 882 per batch
    int N = in_sizes[2] / B;   // pred_scores is [B,N]

    size_t shmem = (size_t)N * (sizeof(float4) + sizeof(int));  // 20 B/box
    frcnn_post<<<B, 1024, shmem, stream>>>(boxes, labels, scores, Hp, Wp, out, B, N);
}